// Round 5
// baseline (43.933 us; speedup 1.0000x reference)
//
#include <hip/hip_runtime.h>
#include <cmath>

#define S_SUB 512
#define T_TR  8192
#define D_IN  8
#define NSEG  4            // segments per subject
#define SEGT  (T_TR/NSEG)  // 2048 trials per segment
#define BLK   256          // threads per block
#define CH    (SEGT/BLK)   // 8 trials per thread
#define NW    (BLK/64)     // 4 waves per block

typedef float f4 __attribute__((ext_vector_type(4)));

// ---------------------------------------------------------------------------
// Kernel 1 (tiny): per-subject parameter chain in f64. Isolated here so the
// streaming kernel avoids erfcinv/erfc register pressure under its 64-VGPR
// occupancy cap. Fa = Phi(-9.9), dF = Phi(0.1)-Phi(-9.9) are host constants.
// ---------------------------------------------------------------------------
__global__ void setup_kernel(const float* __restrict__ u_a,
                             const float* __restrict__ sigmasq,
                             const float* __restrict__ eps_mu,
                             const float* __restrict__ eps_x0,
                             double Fa, double dF,
                             double* __restrict__ params) {   // [S][4]
    int s = blockIdx.x * blockDim.x + threadIdx.x;
    if (s >= S_SUB) return;
    const double RS2 = 0.7071067811865476;     // 1/sqrt(2)
    const double S2  = 1.4142135623730951;     // sqrt(2)
    const double ISQ = 0.3989422804014327;     // 1/sqrt(2*pi)
    double p = fma((double)u_a[s], dF, Fa);
    double z = -S2 * erfcinv(2.0 * p);
    #pragma unroll
    for (int it = 0; it < 2; ++it) {           // Newton polish: Phi(z)=p
        double F   = 0.5 * erfc(-z * RS2);
        double pdf = exp(-0.5 * z * z) * ISQ;
        z -= (F - p) / pdf;
    }
    double a  = 0.99 + 0.1 * z;
    double mu = (double)eps_mu[s];
    double b  = mu * (1.0 - a);
    double x0 = mu + (double)eps_x0[s];
    double sd = sqrt((double)sigmasq[s]);
    params[4*s+0] = a;
    params[4*s+1] = b;
    params[4*s+2] = sd;
    params[4*s+3] = x0;
}

// ---------------------------------------------------------------------------
// Kernel 2: self-seeding fused kernel. One block per (subject, segment); no
// cross-block dependencies. Seed = affine REDUCE over the <=3 preceding
// eps_x segments (L3-hot re-reads, loads issued upfront, predicated on the
// block-uniform seg). Then the validated round-4 pipeline: in-block scan,
// f64 replay into a pad-9 LDS transpose buffer, coalesced phase-B streaming
// of inputs/u_bern + logits + Bernoulli.
// ---------------------------------------------------------------------------
__global__ __launch_bounds__(BLK, 8) void mono_kernel(
    const float* __restrict__ inputs,
    const float* __restrict__ eps_w,
    const float* __restrict__ eps_x,
    const float* __restrict__ u_bern,
    const double* __restrict__ params,
    float* __restrict__ out_x,
    float* __restrict__ out_y)
{
    const int bid  = blockIdx.x;
    const int s    = bid >> 2;
    const int seg  = bid & 3;
    const int tid  = threadIdx.x;
    const int lane = tid & 63;
    const int wid  = tid >> 6;

    __shared__ double2 wtot[NW];
    __shared__ double  xs[BLK * (CH + 1)];   // pad-9 transpose buffer (18 KiB)

    const size_t subjbase = (size_t)s * T_TR;
    const size_t segbase  = subjbase + (size_t)seg * SEGT;
    const size_t base     = segbase + (size_t)tid * CH;

    // ---- issue all eps_x loads upfront (own + preceding segments) ----
    const f4* e4 = (const f4*)(eps_x + base);
    f4 o0 = e4[0];
    f4 o1 = e4[1];
    f4 q0[3], q1[3];
    #pragma unroll
    for (int p = 0; p < NSEG - 1; ++p) {
        if (p < seg) {                        // block-uniform predicate
            const f4* ep = (const f4*)(eps_x + subjbase + (size_t)p * SEGT
                                       + (size_t)tid * CH);
            q0[p] = ep[0];
            q1[p] = ep[1];
        }
    }

    // block-uniform parameters (L2-hot, 32 B)
    const double a  = params[4*s+0];
    const double b  = params[4*s+1];
    const double sd = params[4*s+2];
    double xseed    = params[4*s+3];

    // ---- seed: affine reduce over preceding segments ----
    #pragma unroll
    for (int p = 0; p < NSEG - 1; ++p) {
        if (p < seg) {                        // uniform branch: barriers legal
            float evp[CH];
            evp[0]=q0[p].x; evp[1]=q0[p].y; evp[2]=q0[p].z; evp[3]=q0[p].w;
            evp[4]=q1[p].x; evp[5]=q1[p].y; evp[6]=q1[p].z; evp[7]=q1[p].w;
            double A = 1.0, Bv = 0.0;
            #pragma unroll
            for (int j = 0; j < CH; ++j) {
                double c = fma(sd, (double)evp[j], b);
                Bv = fma(a, Bv, c);
                A *= a;
            }
            // ordered wave reduce (earliest lane first); lane 0 = wave total
            #pragma unroll
            for (int off = 1; off < 64; off <<= 1) {
                double pA = __shfl_down(A, off);
                double pB = __shfl_down(Bv, off);
                Bv = fma(pA, Bv, pB);         // later ∘ earlier
                A  = pA * A;
            }
            if (lane == 0) wtot[wid] = make_double2(A, Bv);
            __syncthreads();
            double CA = wtot[0].x, CB = wtot[0].y;
            #pragma unroll
            for (int w = 1; w < NW; ++w) {
                CB = fma(wtot[w].x, CB, wtot[w].y);
                CA = wtot[w].x * CA;
            }
            xseed = fma(CA, xseed, CB);
            __syncthreads();                  // wtot reused next pass / scan
        }
    }

    // ---- own-segment: local compose + inclusive wave scan ----
    float ev[CH];
    ev[0]=o0.x; ev[1]=o0.y; ev[2]=o0.z; ev[3]=o0.w;
    ev[4]=o1.x; ev[5]=o1.y; ev[6]=o1.z; ev[7]=o1.w;

    double A = 1.0, Bv = 0.0;
    #pragma unroll
    for (int j = 0; j < CH; ++j) {
        double c = fma(sd, (double)ev[j], b);
        Bv = fma(a, Bv, c);
        A *= a;
    }
    #pragma unroll
    for (int off = 1; off < 64; off <<= 1) {
        double pA = __shfl_up(A, off);
        double pB = __shfl_up(Bv, off);
        if (lane >= off) {
            Bv = fma(A, pB, Bv);              // cur ∘ prev
            A  = A * pA;
        }
    }
    if (lane == 63) wtot[wid] = make_double2(A, Bv);
    __syncthreads();

    // exclusive cross-wave prefix
    double PA = 1.0, PB = 0.0;
    for (int w = 0; w < wid; ++w) {
        double2 t = wtot[w];
        PB = fma(t.x, PB, t.y);
        PA = t.x * PA;
    }
    double eA = __shfl_up(A, 1);
    double eB = __shfl_up(Bv, 1);
    if (lane == 0) { eA = 1.0; eB = 0.0; }
    double EB = fma(eA, PB, eB);
    double EA = eA * PA;
    double x  = fma(EA, xseed, EB);           // x at start of this chunk

    // ---- phase A replay: deposit x_t (f64, pre-update) into LDS ----
    #pragma unroll
    for (int j = 0; j < CH; ++j) {
        xs[tid * (CH + 1) + j] = x;
        double c = fma(sd, (double)ev[j], b);
        x = fma(a, x, c);
    }
    __syncthreads();

    // ---- phase B: coalesced streaming (trial = j*BLK + tid) ----
    const float* wp = eps_w + s * D_IN;
    const double w0 = (double)wp[0], w1 = (double)wp[1];
    const double w2 = (double)wp[2], w3 = (double)wp[3];
    const double w4 = (double)wp[4], w5 = (double)wp[5];
    const double w6 = (double)wp[6], w7 = (double)wp[7];

    float uv[CH];
    #pragma unroll
    for (int j = 0; j < CH; ++j)
        uv[j] = u_bern[segbase + j * BLK + tid];

    const f4* in4 = (const f4*)(inputs + segbase * D_IN);
    #pragma unroll
    for (int j = 0; j < CH; ++j) {
        const int t = j * BLK + tid;
        f4 i0 = in4[2*t];
        f4 i1 = in4[2*t + 1];
        double xv = xs[(t >> 3) * (CH + 1) + (t & 7)];
        double dot = fma((double)i0.x, w0,
                     fma((double)i0.y, w1,
                     fma((double)i0.z, w2,
                     fma((double)i0.w, w3,
                     fma((double)i1.x, w4,
                     fma((double)i1.y, w5,
                     fma((double)i1.z, w6, (double)i1.w * w7)))))));
        double L = xv + dot;
        double E = exp(-L);
        out_y[segbase + t] = ((double)uv[j] * (1.0 + E) < 1.0) ? 1.0f : 0.0f;
        out_x[segbase + t] = (float)xv;
    }
}

extern "C" void kernel_launch(void* const* d_in, const int* in_sizes, int n_in,
                              void* d_out, int out_size, void* d_ws, size_t ws_size,
                              hipStream_t stream) {
    const float* inputs  = (const float*)d_in[0];   // [S,T,D]
    const float* eps_w   = (const float*)d_in[1];   // [S,D]
    const float* u_a     = (const float*)d_in[2];   // [S]
    const float* sigmasq = (const float*)d_in[3];   // [S]
    const float* eps_mu  = (const float*)d_in[4];   // [S]
    const float* eps_x0  = (const float*)d_in[5];   // [S]
    const float* eps_x   = (const float*)d_in[6];   // [S,T]
    const float* u_bern  = (const float*)d_in[7];   // [S,T]

    float*  out    = (float*)d_out;                 // [x | y] f32
    double* params = (double*)d_ws;                 // 16 KiB

    // input-independent truncation constants (host f64 libm)
    const double RS2 = 0.7071067811865476;
    const double Fa  = 0.5 * erfc(9.9 * RS2);       // Phi(-9.9)
    const double Fb  = 0.5 * erfc(-0.1 * RS2);      // Phi(0.1)
    const double dF  = Fb - Fa;

    setup_kernel<<<2, 256, 0, stream>>>(u_a, sigmasq, eps_mu, eps_x0, Fa, dF, params);
    mono_kernel<<<S_SUB*NSEG, BLK, 0, stream>>>(inputs, eps_w, eps_x, u_bern,
                                                params,
                                                out, out + (size_t)S_SUB * T_TR);
}